// Round 1
// baseline (721.236 us; speedup 1.0000x reference)
//
#include <hip/hip_runtime.h>
#include <math.h>

#define CH 256

__device__ __forceinline__ float gelu_exact(float v) {
    return 0.5f * v * (1.0f + erff(v * 0.70710678118654752f));
}

// out[M x 256] = A[M x K] @ W[K x 256] + bias, optional exact GELU.
// BM=128, BN=64, BK=16; 256 threads; each thread computes 8x4.
template<bool DOGELU>
__global__ __launch_bounds__(256) void gemm_kernel(const float* __restrict__ A,
                                                   const float* __restrict__ W,
                                                   const float* __restrict__ bias,
                                                   float* __restrict__ out,
                                                   int M, int K)
{
    const int BM = 128, BN = 64, BK = 16;
    __shared__ float As[BK][BM + 4];   // [16][132], row = 528B (16B aligned)
    __shared__ float Bs[BK][BN + 4];   // [16][68],  row = 272B (16B aligned)

    int tid = threadIdx.x;
    int m0 = blockIdx.x * BM;
    int n0 = blockIdx.y * BN;
    int ty = tid >> 4;        // 0..15 -> 8 rows each
    int tx = tid & 15;        // 0..15 -> 4 cols each

    float acc[8][4];
#pragma unroll
    for (int i = 0; i < 8; i++)
#pragma unroll
        for (int j = 0; j < 4; j++) acc[i][j] = 0.f;

    const int arow = tid >> 1;          // 0..127
    const int ak   = (tid & 1) * 8;     // 0 or 8
    const int brow = tid >> 4;          // 0..15 (k)
    const int bcol = (tid & 15) * 4;    // 0..60
    const bool kvec = ((K & 3) == 0);   // float4 A loads only if K aligned

    for (int k0 = 0; k0 < K; k0 += BK) {
        // ---- stage A tile (transposed into As[k][row]) ----
        {
            int gr = m0 + arow;
            bool rowok = gr < M;
            if (rowok && kvec && (k0 + BK <= K)) {
                const float* src = A + (size_t)gr * K + k0 + ak;
                float4 v0 = *(const float4*)(src);
                float4 v1 = *(const float4*)(src + 4);
                As[ak + 0][arow] = v0.x; As[ak + 1][arow] = v0.y;
                As[ak + 2][arow] = v0.z; As[ak + 3][arow] = v0.w;
                As[ak + 4][arow] = v1.x; As[ak + 5][arow] = v1.y;
                As[ak + 6][arow] = v1.z; As[ak + 7][arow] = v1.w;
            } else {
#pragma unroll
                for (int i = 0; i < 8; i++) {
                    int k = k0 + ak + i;
                    As[ak + i][arow] = (rowok && k < K) ? A[(size_t)gr * K + k] : 0.f;
                }
            }
        }
        // ---- stage B tile ----
        {
            int gk = k0 + brow;
            if (gk < K) {
                float4 v = *(const float4*)(W + (size_t)gk * CH + n0 + bcol);
                Bs[brow][bcol + 0] = v.x; Bs[brow][bcol + 1] = v.y;
                Bs[brow][bcol + 2] = v.z; Bs[brow][bcol + 3] = v.w;
            } else {
                Bs[brow][bcol + 0] = 0.f; Bs[brow][bcol + 1] = 0.f;
                Bs[brow][bcol + 2] = 0.f; Bs[brow][bcol + 3] = 0.f;
            }
        }
        __syncthreads();

#pragma unroll
        for (int kk = 0; kk < BK; kk++) {
            float a[8], b[4];
            *(float4*)&a[0] = *(const float4*)&As[kk][ty * 8];
            *(float4*)&a[4] = *(const float4*)&As[kk][ty * 8 + 4];
            *(float4*)&b[0] = *(const float4*)&Bs[kk][tx * 4];
#pragma unroll
            for (int i = 0; i < 8; i++)
#pragma unroll
                for (int j = 0; j < 4; j++)
                    acc[i][j] = fmaf(a[i], b[j], acc[i][j]);
        }
        __syncthreads();
    }

    // ---- epilogue: bias (+ GELU), coalesced float4 stores ----
    float b4[4];
    *(float4*)&b4[0] = *(const float4*)(bias + n0 + tx * 4);
#pragma unroll
    for (int i = 0; i < 8; i++) {
        int r = m0 + ty * 8 + i;
        if (r < M) {
            float o[4];
#pragma unroll
            for (int j = 0; j < 4; j++) {
                float v = acc[i][j] + b4[j];
                o[j] = DOGELU ? gelu_exact(v) : v;
            }
            *(float4*)(out + (size_t)r * CH + n0 + tx * 4) = *(float4*)&o[0];
        }
    }
}

__global__ void zero_int_kernel(int* p, int n) {
    int i = blockIdx.x * blockDim.x + threadIdx.x;
    if (i < n) p[i] = 0;
}

__global__ void degree_kernel(const int* __restrict__ ei, int E, int* deg) {
    int e = blockIdx.x * blockDim.x + threadIdx.x;
    if (e < E) atomicAdd(&deg[ei[E + e]], 1);
}

// Single-block exclusive scan over degrees -> row_ptr, fill_pos, inv_cnt.
__global__ void scan_kernel(const int* __restrict__ deg, int* row_ptr, int* fill_pos,
                            float* inv, int N, int E) {
    __shared__ int part[256];
    int t = threadIdx.x;
    int chunk = (N + 255) >> 8;
    int s = t * chunk;
    int e = min(s + chunk, N);
    int sum = 0;
    for (int i = s; i < e; i++) sum += deg[i];
    part[t] = sum;
    __syncthreads();
    for (int off = 1; off < 256; off <<= 1) {
        int v = (t >= off) ? part[t - off] : 0;
        __syncthreads();
        part[t] += v;
        __syncthreads();
    }
    int run = (t == 0) ? 0 : part[t - 1];
    for (int i = s; i < e; i++) {
        row_ptr[i] = run;
        fill_pos[i] = run;
        int d = deg[i];
        run += d;
        inv[i] = 1.0f / fmaxf((float)d, 1.0f);
    }
    if (t == 255) row_ptr[N] = E;
}

__global__ void fill_kernel(const int* __restrict__ ei, int E, int* fill_pos, int* colv) {
    int e = blockIdx.x * blockDim.x + threadIdx.x;
    if (e < E) {
        int p = atomicAdd(&fill_pos[ei[E + e]], 1);
        colv[p] = ei[e];
    }
}

// One wave per node: 64 lanes x float4 = one 256-ch row per iteration.
__global__ void agg_kernel(const float* __restrict__ t, const int* __restrict__ row_ptr,
                           const int* __restrict__ colv, const float* __restrict__ inv,
                           float* __restrict__ agg, int N) {
    int n = blockIdx.x * 4 + (threadIdx.x >> 6);
    if (n >= N) return;
    int lane = threadIdx.x & 63;
    int s = row_ptr[n], e = row_ptr[n + 1];
    float a0 = 0.f, a1 = 0.f, a2 = 0.f, a3 = 0.f;
    for (int j = s; j < e; j++) {
        const float* p = t + (size_t)colv[j] * CH + lane * 4;
        float4 v = *(const float4*)p;
        a0 += v.x; a1 += v.y; a2 += v.z; a3 += v.w;
    }
    float sc = inv[n];
    float o[4] = {a0 * sc, a1 * sc, a2 * sc, a3 * sc};
    *(float4*)(agg + (size_t)n * CH + lane * 4) = *(float4*)&o[0];
}

__global__ void mean_kernel(const float* __restrict__ h, float* __restrict__ out, int N) {
    int n = blockIdx.x * 4 + (threadIdx.x >> 6);
    if (n >= N) return;
    int lane = threadIdx.x & 63;
    float4 v = *(const float4*)(h + (size_t)n * CH + lane * 4);
    float s = v.x + v.y + v.z + v.w;
#pragma unroll
    for (int off = 32; off; off >>= 1) s += __shfl_down(s, off, 64);
    if (lane == 0) out[n] = s * (1.0f / 256.0f);
}

extern "C" void kernel_launch(void* const* d_in, const int* in_sizes, int n_in,
                              void* d_out, int out_size, void* d_ws, size_t ws_size,
                              hipStream_t stream) {
    const float* x       = (const float*)d_in[0];
    const int*   ei      = (const int*)d_in[1];
    const float* W_embed = (const float*)d_in[2];
    const float* b_embed = (const float*)d_in[3];
    const float* W1      = (const float*)d_in[4];
    const float* b1      = (const float*)d_in[5];
    const float* W2      = (const float*)d_in[6];
    const float* b2      = (const float*)d_in[7];
    float* out = (float*)d_out;

    int N = in_sizes[0] / 118;
    int E = in_sizes[1] / 2;

    // workspace layout
    float* h        = (float*)d_ws;                 // N*256
    float* t        = h + (size_t)N * CH;           // N*256
    float* agg      = t + (size_t)N * CH;           // N*256
    float* inv      = agg + (size_t)N * CH;         // N
    int*   deg      = (int*)(inv + N);              // N
    int*   row_ptr  = deg + N;                      // N+1
    int*   fill_pos = row_ptr + (N + 1);            // N
    int*   colv     = fill_pos + N;                 // E

    // CSR build (per launch; deterministic work)
    zero_int_kernel<<<(N + 255) / 256, 256, 0, stream>>>(deg, N);
    degree_kernel<<<(E + 255) / 256, 256, 0, stream>>>(ei, E, deg);
    scan_kernel<<<1, 256, 0, stream>>>(deg, row_ptr, fill_pos, inv, N, E);
    fill_kernel<<<(E + 255) / 256, 256, 0, stream>>>(ei, E, fill_pos, colv);

    dim3 gg((N + 127) / 128, 4);
    // embed: h = x @ W_embed + b_embed
    gemm_kernel<false><<<gg, 256, 0, stream>>>(x, W_embed, b_embed, h, N, 118);
    for (int l = 0; l < 4; l++) {
        // t = gelu(h @ W1 + b1)  (node-side; gather commutes with dense)
        gemm_kernel<true><<<gg, 256, 0, stream>>>(h, W1 + (size_t)l * CH * CH,
                                                  b1 + (size_t)l * CH, t, N, CH);
        // agg = mean-scatter of t[src] over dst
        agg_kernel<<<(N + 3) / 4, 256, 0, stream>>>(t, row_ptr, colv, inv, agg, N);
        // h = gelu(agg @ W2 + b2)
        gemm_kernel<true><<<gg, 256, 0, stream>>>(agg, W2 + (size_t)l * CH * CH,
                                                  b2 + (size_t)l * CH, h, N, CH);
    }
    mean_kernel<<<(N + 3) / 4, 256, 0, stream>>>(h, out, N);
}